// Round 1
// baseline (407.891 us; speedup 1.0000x reference)
//
#include <hip/hip_runtime.h>
#include <math.h>

// Problem constants (reference: VOCAB=10000, HID=256, B=64, T=64)
#define VOCABN 10000
#define HIDN   256
#define GATES  1024   // 4*HID
#define BN     64
#define TN     64
#define BT     4096   // B*T
#define NCT    625    // vocab col-tiles of 16 (10000 = 625*16 exactly)

typedef unsigned int       u32;
typedef unsigned short     u16;
typedef unsigned long long u64;
typedef float v4f __attribute__((ext_vector_type(4)));
typedef short v8s __attribute__((ext_vector_type(8)));

// Sentinel for the h-exchange ring: four bf16 lanes of 0xFFFF (= -NaN each).
// h = sigmoid*tanh products are finite with |h| < 1, so f2bf(h) can never be
// 0xFFFF; a packed u64 of real h data can never equal SENT.
#define SENT 0xFFFFFFFFFFFFFFFFULL

__device__ __forceinline__ float bf2f(u16 u) {
    return __uint_as_float(((u32)u) << 16);
}
__device__ __forceinline__ u16 f2bf(float f) {          // round-to-nearest-even
    u32 u = __float_as_uint(f);
    u += 0x7FFFu + ((u >> 16) & 1u);
    return (u16)(u >> 16);
}
__device__ __forceinline__ float fast_sigmoid(float x) {
    return 1.0f / (1.0f + __expf(-x));
}
__device__ __forceinline__ float fast_tanh(float x) {
    float e = __expf(-2.0f * fabsf(x));
    float t = (1.0f - e) / (1.0f + e);
    return copysignf(t, x);
}
__device__ __forceinline__ u64 llc_load(const u64* p) {
    return __hip_atomic_load(p, __ATOMIC_RELAXED, __HIP_MEMORY_SCOPE_AGENT);
}
__device__ __forceinline__ void llc_store(u64* p, u64 v) {
    __hip_atomic_store(p, v, __ATOMIC_RELAXED, __HIP_MEMORY_SCOPE_AGENT);
}

// ---------------------------------------------------------------------------
// fp32 [HIDN][ncols] tile c -> bf16 MFMA B-fragment layout [c][8 q][64 l][8].
// Fragment (c,q), lane l holds B[k = q*32 + (l>>4)*8 + j][n = c*16 + (l&15)].
// Plain uint4 stores (writer-L2 cached; cross-kernel visibility via the
// end-of-dispatch flush — consumers are always later launches).
// ---------------------------------------------------------------------------
__device__ __forceinline__ void wfrag_dev(
    const float* __restrict__ src, u16* __restrict__ dst, int ncols, int c,
    int t, u16 lt[HIDN][16])
{
    const float* s = src + (size_t)t * ncols + c * 16;
    #pragma unroll
    for (int j4 = 0; j4 < 4; ++j4) {
        float4 v = *(const float4*)(s + j4 * 4);
        lt[t][j4*4+0] = f2bf(v.x);
        lt[t][j4*4+1] = f2bf(v.y);
        lt[t][j4*4+2] = f2bf(v.z);
        lt[t][j4*4+3] = f2bf(v.w);
    }
    __syncthreads();
    #pragma unroll
    for (int h = 0; h < 2; ++h) {
        int f = t + h * 256;             // frag id = q*64 + l
        int q = f >> 6, l = f & 63;
        int m = l & 15, kb = q * 32 + ((l >> 4) & 3) * 8;
        u32 w[4];
        #pragma unroll
        for (int j = 0; j < 4; ++j)
            w[j] = (u32)lt[kb + 2*j][m] | ((u32)lt[kb + 2*j + 1][m] << 16);
        *(uint4*)(dst + (((size_t)c * 8 + q) * 64 + l) * 8) =
            make_uint4(w[0], w[1], w[2], w[3]);
    }
}

// ---------------------------------------------------------------------------
// wfrag for both W_lstm halves (128 blocks) — fallback-path prep. Blocks
// 0..63 also sentinel-fill the 4-deep Hx ring (16384 u64 = 64 blk x 256 thr);
// plain stores, visible to k_plstm's LLC loads via the end-of-dispatch flush
// (same guarantee the old bar-zeroing relied on).
// ---------------------------------------------------------------------------
__global__ __launch_bounds__(256) void k_wfrag2(
    const float* __restrict__ W_lstm,
    u16* __restrict__ Wxf, u16* __restrict__ Whf,
    u64* __restrict__ Hx64)          // [4*BN*HIDN/4] u64 exchange ring
{
    __shared__ u16 lt[HIDN][16];
    const int bid = blockIdx.x;
    if (bid < 64) {
        Hx64[(size_t)bid * 256 + threadIdx.x] = SENT;
        wfrag_dev(W_lstm, Wxf, GATES, bid, threadIdx.x, lt);
    } else {
        wfrag_dev(W_lstm + (size_t)HIDN * GATES, Whf, GATES, bid - 64,
                  threadIdx.x, lt);
    }
}

// ---------------------------------------------------------------------------
// ALL THREE weight transforms in one launch (753 blocks) — wide-ws path.
//   0..63: W_lstm x-part -> Wxf (+ Hx sentinel fill) | 64..127: h-part -> Whf
//   | 128..752: W_dense
// ---------------------------------------------------------------------------
__global__ __launch_bounds__(256) void k_wfrag3(
    const float* __restrict__ W_lstm,
    const float* __restrict__ W_dense,
    u16* __restrict__ Wxf, u16* __restrict__ Whf, u16* __restrict__ Wf,
    u64* __restrict__ Hx64)
{
    __shared__ u16 lt[HIDN][16];
    const int bid = blockIdx.x;
    if (bid < 64) {
        Hx64[(size_t)bid * 256 + threadIdx.x] = SENT;
        wfrag_dev(W_lstm, Wxf, GATES, bid, threadIdx.x, lt);
    } else if (bid < 128) {
        wfrag_dev(W_lstm + (size_t)HIDN * GATES, Whf, GATES, bid - 64,
                  threadIdx.x, lt);
    } else {
        wfrag_dev(W_dense, Wf, VOCABN, bid - 128, threadIdx.x, lt);
    }
}

// ---------------------------------------------------------------------------
// wfrag for W_dense (625 blocks) — fallback path, runs AFTER plstm (Wf
// aliases gx there).
// ---------------------------------------------------------------------------
__global__ __launch_bounds__(256) void k_wfrag(
    const float* __restrict__ src,   // [HIDN][ncols]
    u16*         __restrict__ dst,   // [nct][8][64][8]
    int ncols)
{
    __shared__ u16 lt[HIDN][16];
    wfrag_dev(src, dst, ncols, blockIdx.x, threadIdx.x, lt);
}

// ---------------------------------------------------------------------------
// Kernel 1 (MFMA): gates_x = E[idx] @ W_x + b_lstm. 256 blocks x 16 rows.
// gx stays fp32: bf16 gx cost plstm +14us (R9 vs R10 A/B).
// ---------------------------------------------------------------------------
__global__ __launch_bounds__(256) void k_xgates(
    const int*   __restrict__ idx,   // [BT]
    const float* __restrict__ E,     // [VOCAB][HIDN]
    const u16*   __restrict__ Wxf,   // [64][8][64][8]
    const float* __restrict__ bl,    // [GATES]
    float*       __restrict__ gx)    // [BT][GATES]
{
    const int r0   = blockIdx.x * 16;
    const int tid  = threadIdx.x;
    const int w    = tid >> 6, lane = tid & 63;
    const int m    = lane & 15, quad = lane >> 4;

    v8s a[8];
    {
        const float* e = E + (size_t)idx[r0 + m] * HIDN + quad * 8;
        #pragma unroll
        for (int q = 0; q < 8; ++q) {
            float4 x0 = *(const float4*)(e + q * 32);
            float4 x1 = *(const float4*)(e + q * 32 + 4);
            uint4 t4 = make_uint4(
                (u32)f2bf(x0.x) | ((u32)f2bf(x0.y) << 16),
                (u32)f2bf(x0.z) | ((u32)f2bf(x0.w) << 16),
                (u32)f2bf(x1.x) | ((u32)f2bf(x1.y) << 16),
                (u32)f2bf(x1.z) | ((u32)f2bf(x1.w) << 16));
            a[q] = *(v8s*)&t4;
        }
    }

    for (int c = w; c < GATES / 16; c += 4) {
        v4f acc = {0.f, 0.f, 0.f, 0.f};
        #pragma unroll
        for (int q = 0; q < 8; ++q) {
            v8s b = *(const v8s*)(Wxf + (((size_t)c * 8 + q) * 64 + lane) * 8);
            acc = __builtin_amdgcn_mfma_f32_16x16x32_bf16(a[q], b, acc, 0, 0, 0);
        }
        const int col = c * 16 + m;
        const float bv = bl[col];
        #pragma unroll
        for (int r = 0; r < 4; ++r)   // D: col=lane&15, row=quad*4+r (m89/m91)
            gx[(size_t)(r0 + quad * 4 + r) * GATES + col] = acc[r] + bv;
    }
}

// ---------------------------------------------------------------------------
// Kernel 2 (persistent MFMA LSTM — sentinel-exchange redesign of the proven
// 209us R10/R14 kernel; MFMA / W-layout / cell math VERBATIM):
// 64 blocks = 4 row-groups(16 rows) x 16 unit-slices. W_h slice LDS-resident.
//
// Sync redesign (this round): the counter barrier (4+ serialized LLC round
// trips per step: publish drain -> 16 RMWs -> poll detect -> h load) is
// replaced by SIGNAL-IN-DATA polling:
//  * Hx is a 4-deep ring [4][BN][HIDN]; step t publishes into buf t&3,
//    consumed at step t+1 from buf t&3.
//  * Consumers poll the h u64s directly until != SENT — the signal arrives
//    with the data in the SAME round trip. No counter, no RMW.
//  * Each block pre-clears (SENT) its slice of buf (t+1)&3 at the TOP of
//    step t; the clear is drained (vmcnt 0) at the mid-step __syncthreads,
//    i.e. ordered BEFORE this block's data(t) publish. Message passing via
//    the LLC (same drain->visible guarantee the old kernel's barrier used):
//    any consumer that accepted data(t) therefore has the clear visible, so
//    it can never accept data(t-3) as data(t+1). The poll itself bounds the
//    inter-block lead to <=1 step (a block cannot pass its step-t poll until
//    every rg-block published data(t-1)), which makes the clear race-free:
//    the old readers of the cleared buffer finished 2 steps ago, and their
//    reads retired before the publishes we already observed.
//  * gl gate-exchange is double-buffered (t&1) -> ONE __syncthreads per
//    step (barrier rendezvous separates writer epoch t+1 from reader epoch
//    t-1). Old structure had 3 syncs + cross-block barrier.
// Prep kernels sentinel-fill the whole ring so step 1's poll of buf0 (never
// pre-cleared in-loop) is safe. Runs ALONE (R7/R8: co-running dense cost
// this kernel 1.7x).
// ---------------------------------------------------------------------------
__global__ __launch_bounds__(256) void k_plstm(
    const u16*   __restrict__ Whf,   // [64 ct][8][64][8] h-part frags
    const float* __restrict__ gx,    // [BT][GATES]
    u16*                      Hx,    // [4][BN][HIDN] bf16 exchange ring (LLC)
    u16*         __restrict__ Hb)    // [BT][HIDN] bf16 output
{
    __shared__ uint4 Wl4[4 * 512];       // 32 KB: [ct][8 q][64 l][8] u16
    __shared__ float gl[2][4][16][16];   // 8 KB gate exchange, double-buffered

    const int tid  = threadIdx.x;
    const int rg   = blockIdx.x >> 4;    // row group: batch rows rg*16..+15
    const int ns   = blockIdx.x & 15;    // unit slice: units ns*16..+15
    const int u0   = ns * 16;
    const int w    = tid >> 6;           // wave = gate type (i,j,f,o)
    const int lane = tid & 63;
    const int m    = lane & 15, kq = lane >> 4;

    {   // load W_h slice: tiles c = w'*16 + ns, 8 KB contiguous each
        const uint4* src = (const uint4*)Whf;
        #pragma unroll
        for (int i = 0; i < 8; ++i) {
            int e  = tid + i * 256;          // [0, 2048)
            int ct = e >> 9, off = e & 511;  // 512 uint4 per tile
            Wl4[e] = src[(size_t)(ct * 16 + ns) * 512 + off];
        }
    }
    {   // zero gl[0] so t=0 reads 0 for the h@W_h term
        float* g0 = (float*)gl[0];
        #pragma unroll
        for (int j = 0; j < 4; ++j) g0[tid * 4 + j] = 0.0f;
    }
    __syncthreads();

    const u16* Wl = (const u16*)Wl4;

    const int r = tid >> 4, u = tid & 15;
    const int b = rg * 16 + r;                       // batch row
    const float* gxp = gx + (size_t)b * TN * GATES + u0 + u;
    u16* hbp = Hb + (size_t)b * TN * HIDN + u0 + u;
    const int hxw = b * HIDN + u0 + u;               // Hx elem offset (in-buf)
    const int aoff = (rg * 16 + m) * HIDN + kq * 8;  // a-frag elem offset
    u64* const hx64 = (u64*)Hx;
    // this block's publish slice as u64 indices (64 u64s, tid<64 clears them)
    const int cidx = (rg * 16 + (tid >> 2)) * (HIDN / 4) + ns * 4 + (tid & 3);

    float cstate = 0.0f;
    float4 gxr;
    gxr.x = gxp[0]; gxr.y = gxp[256]; gxr.z = gxp[512]; gxr.w = gxp[768];

    for (int t = 0; t < TN; ++t) {
        // prefetch next step's x-gates early (hide HBM latency)
        float4 gxn = gxr;
        if (t + 1 < TN) {
            const float* p = gxp + (size_t)(t + 1) * GATES;
            gxn.x = p[0]; gxn.y = p[256]; gxn.z = p[512]; gxn.w = p[768];
        }

        // pre-clear next publish buffer (see header comment for ordering
        // proof). Fire-and-forget; drained by the __syncthreads below.
        if (t + 1 < TN && tid < 64)
            llc_store(hx64 + (size_t)((t + 1) & 3) * (BN * HIDN / 4) + cidx,
                      SENT);

        if (t > 0) {
            // poll-load a-frags from the ring: data != SENT IS the signal
            const u64* hsrc =
                (const u64*)(Hx + (size_t)((t - 1) & 3) * (BN * HIDN) + aoff);
            u64 d[16];
            #pragma unroll
            for (int q = 0; q < 8; ++q) {        // issue all 16 loads first
                d[2 * q]     = llc_load(hsrc + q * 8);
                d[2 * q + 1] = llc_load(hsrc + q * 8 + 1);
            }
            #pragma unroll
            for (int i = 0; i < 16; ++i)
                while (d[i] == SENT)
                    d[i] = llc_load(hsrc + (i >> 1) * 8 + (i & 1));

            v4f acc = {0.f, 0.f, 0.f, 0.f};
            #pragma unroll
            for (int q = 0; q < 8; ++q) {
                union { u64 dd[2]; v8s v; } av;
                av.dd[0] = d[2 * q];
                av.dd[1] = d[2 * q + 1];
                v8s bf = *(const v8s*)(Wl + ((w * 8 + q) * 64 + lane) * 8);
                acc = __builtin_amdgcn_mfma_f32_16x16x32_bf16(av.v, bf, acc,
                                                              0, 0, 0);
            }
            #pragma unroll
            for (int rr = 0; rr < 4; ++rr)   // row = kq*4+rr, col(unit) = m
                gl[t & 1][w][kq * 4 + rr][m] = acc[rr];
        }
        __syncthreads();   // gl[t&1] ready; clear stores drained (vmcnt 0)
                           // BEFORE the data(t) publish below

        {   // cell update for (r, u); c stays in a register
            float ai = gl[t & 1][0][r][u] + gxr.x;
            float aj = gl[t & 1][1][r][u] + gxr.y;
            float af = gl[t & 1][2][r][u] + gxr.z;
            float ao = gl[t & 1][3][r][u] + gxr.w;
            float ig = fast_sigmoid(ai);
            float fg = fast_sigmoid(af + 1.0f);      // forget_bias = 1.0
            float og = fast_sigmoid(ao);
            float jt = fast_tanh(aj);
            cstate = fg * cstate + ig * jt;
            float hn = og * fast_tanh(cstate);
            u32 hv = f2bf(hn);
            hbp[(size_t)t * HIDN] = (u16)hv;

            if (t + 1 < TN) {
                // pack 4 consecutive units (same row, lanes tid..tid+3) into
                // one u64 and publish via relaxed agent atomic store -> LLC
                u32 p1 = __shfl_down(hv, 1);
                u32 p2 = __shfl_down(hv, 2);
                u32 p3 = __shfl_down(hv, 3);
                if ((tid & 3) == 0) {
                    u64 pk = (u64)(hv | (p1 << 16))
                           | ((u64)(p2 | (p3 << 16)) << 32);
                    u64* dst =
                        (u64*)(Hx + (size_t)(t & 3) * (BN * HIDN) + hxw);
                    llc_store(dst, pk);
                }
            }
        }
        // no end-of-step barrier: next iteration's gl write targets the
        // other gl buffer, and the step-t __syncthreads rendezvous already
        // separates it from step t-1's readers.
        gxr = gxn;
    }
}

// ---------------------------------------------------------------------------
// Kernel 3 (MFMA dense, 8-way vocab split — R14 verbatim): 512 blocks =
// 64 row-groups(64 rows, 4 register-resident a-frag row-tiles) x 8 vocab
// eighths (~640 KB Wf each, L2-resident per XCD under round-robin %8).
// NOTE: R16's fused target/final epilogue regressed +33us (conditional
// LLC store in the hot loop) — keep the sweep pure.
// ---------------------------------------------------------------------------
__global__ __launch_bounds__(256, 1) void k_dense(
    const u16*   __restrict__ Hb,    // [BT][HIDN] bf16
    const u16*   __restrict__ Wf,    // [625][8][64][8]
    const float* __restrict__ bd,    // [VOCAB]
    float*       __restrict__ S)     // [8][BT] partial sumexp
{
    __shared__ float Sl[64];
    const int bid = blockIdx.x;
    const int hv  = bid & 7;                    // vocab eighth (XCD-aligned)
    const int rg  = bid >> 3;                   // 0..63
    const int r0  = rg * 64;
    const int tid = threadIdx.x;
    const int w   = tid >> 6, lane = tid & 63;
    const int m   = lane & 15, kq = lane >> 4;

    if (tid < 64) Sl[tid] = 0.0f;

    v8s a[4][8];
    #pragma unroll
    for (int rt = 0; rt < 4; ++rt) {
        const u16* hrow = Hb + (size_t)(r0 + rt * 16 + m) * HIDN + kq * 8;
        #pragma unroll
        for (int q = 0; q < 8; ++q)
            a[rt][q] = *(const v8s*)(hrow + q * 32);
    }
    __syncthreads();

    float s[4][4] = {{0.f,0.f,0.f,0.f},{0.f,0.f,0.f,0.f},
                     {0.f,0.f,0.f,0.f},{0.f,0.f,0.f,0.f}};
    const int cbeg = (hv * NCT) >> 3;
    const int cend = ((hv + 1) * NCT) >> 3;
    for (int c = cbeg + w; c < cend; c += 4) {
        v4f acc[4] = {{0.f,0.f,0.f,0.f},{0.f,0.f,0.f,0.f},
                      {0.f,0.f,0.f,0.f},{0.f,0.f,0.f,0.f}};
        #pragma unroll
        for (int q = 0; q < 8; ++q) {
            v8s bq = *(const v8s*)(Wf + (((size_t)c * 8 + q) * 64 + lane) * 8);
            #pragma unroll
            for (int rt = 0; rt < 4; ++rt)
                acc[rt] = __builtin_amdgcn_mfma_f32_16x16x32_bf16(
                              a[rt][q], bq, acc[rt], 0, 0, 0);
        }
        const float bv = bd[c * 16 + m];
        #pragma unroll
        for (int rt = 0; rt < 4; ++rt)
            #pragma unroll
            for (int r = 0; r < 4; ++r)
                s[rt][r] += __expf(acc[rt][r] + bv);
    }

    #pragma unroll
    for (int rt = 0; rt < 4; ++rt)
        #pragma unroll
        for (int r = 0; r < 4; ++r)
            atomicAdd(&Sl[rt * 16 + kq * 4 + r], s[rt][r]);
    __syncthreads();
    if (tid < 64) S[(size_t)hv * BT + r0 + tid] = Sl[tid];
}

// ---------------------------------------------------------------------------
// Kernel 4 (target + final fused — R14 verbatim): per row, dot h with the
// target's W column (32 thr/row), then ppl = exp(log(sum S) - logit).
// ---------------------------------------------------------------------------
__global__ __launch_bounds__(256) void k_target(
    const u16*   __restrict__ Hb,
    const u16*   __restrict__ Wf,
    const float* __restrict__ bd,
    const int*   __restrict__ tgt,
    const float* __restrict__ S,     // [8][BT]
    float*       __restrict__ out)   // [BT]
{
    const int tid = threadIdx.x;
    const int row = blockIdx.x * 8 + (tid >> 5);
    const int t   = tid & 31;
    const int q   = t >> 2, lq = t & 3;
    const int v   = tgt[row];
    const int c   = v >> 4, vm = v & 15;
    const int kb  = q * 32 + lq * 8;

    v8s h  = *(const v8s*)(Hb + (size_t)row * HIDN + kb);
    v8s wv = *(const v8s*)(Wf + (((size_t)c * 8 + q) * 64 + lq * 16 + vm) * 8);
    float acc = 0.0f;
    #pragma unroll
    for (int j = 0; j < 8; ++j)
        acc = fmaf(bf2f((u16)h[j]), bf2f((u16)wv[j]), acc);
    #pragma unroll
    for (int off = 16; off >= 1; off >>= 1)
        acc += __shfl_down(acc, off, 32);
    if (t == 0) {
        float tlv = acc + bd[v];
        float sum = 0.0f;
        #pragma unroll
        for (int p = 0; p < 8; ++p) sum += S[(size_t)p * BT + row];
        out[row] = __expf(__logf(sum) - tlv);
    }
}

// ---------------------------------------------------------------------------
extern "C" void kernel_launch(void* const* d_in, const int* in_sizes, int n_in,
                              void* d_out, int out_size, void* d_ws, size_t ws_size,
                              hipStream_t stream) {
    const int*   input   = (const int*)  d_in[0];   // [B,T]
    const int*   targets = (const int*)  d_in[1];   // [B,T]
    const float* E       = (const float*)d_in[2];   // [VOCAB,HID]
    const float* W_lstm  = (const float*)d_in[3];   // [2H,4H]
    const float* b_lstm  = (const float*)d_in[4];   // [4H]
    const float* W_dense = (const float*)d_in[5];   // [HID,VOCAB]
    const float* b_dense = (const float*)d_in[6];   // [VOCAB]
    float* out = (float*)d_out;                     // [B,T] perplexity

    char* ws = (char*)d_ws;
    const bool wide = (ws_size >= ((size_t)25 << 20));

    if (wide) {
        // 5-node layout: Wf gets its own region; ALL weight transforms in
        // one prep node before xgates. (~24.5 MB)
        //  [0,16M): gx | [16M,21.12M): Wf | [21.25M,23.25M): Hb
        //  [23.25M,+512K): Whf | [23.75M,+512K): Wxf
        //  [24.25M,+128K): Hx (4-deep ring) | [24.25M+128K,+128K): S
        float* gx  = (float*)ws;
        u16*   Wf  = (u16*)(ws + ((size_t)16 << 20));
        u16*   Hb  = (u16*)(ws + ((size_t)21 << 20) + ((size_t)256 << 10));
        u16*   Whf = (u16*)(ws + ((size_t)23 << 20) + ((size_t)256 << 10));
        u16*   Wxf = (u16*)(ws + ((size_t)23 << 20) + ((size_t)768 << 10));
        u16*   Hx  = (u16*)(ws + ((size_t)24 << 20) + ((size_t)256 << 10));
        float* S   = (float*)(ws + ((size_t)24 << 20) + ((size_t)384 << 10));

        k_wfrag3<<<753,     256, 0, stream>>>(W_lstm, W_dense, Wxf, Whf, Wf,
                                              (u64*)Hx);
        k_xgates<<<BT / 16, 256, 0, stream>>>(input, E, Wxf, b_lstm, gx);
        k_plstm <<<64,      256, 0, stream>>>(Whf, gx, Hx, Hb);
        k_dense <<<512,     256, 0, stream>>>(Hb, Wf, b_dense, S);
        k_target<<<BT / 8,  256, 0, stream>>>(Hb, Wf, b_dense, targets, S, out);
    } else {
        // 6-node fallback (Wf aliases gx after plstm).
        //  [0,16M): gx/Wf | [16M,18M): Hb | [18M,+512K): Whf
        //  [18.5M,+512K): Wxf | [19M,+128K): Hx | [19M+128K,+128K): S
        float* gx  = (float*)ws;
        u16*   Wf  = (u16*)ws;
        u16*   Hb  = (u16*)(ws + ((size_t)16 << 20));
        u16*   Whf = (u16*)(ws + ((size_t)18 << 20));
        u16*   Wxf = (u16*)(ws + ((size_t)18 << 20) + ((size_t)512 << 10));
        u16*   Hx  = (u16*)(ws + ((size_t)19 << 20));
        float* S   = (float*)(ws + ((size_t)19 << 20) + ((size_t)128 << 10));

        k_wfrag2<<<128,     256, 0, stream>>>(W_lstm, Wxf, Whf, (u64*)Hx);
        k_xgates<<<BT / 16, 256, 0, stream>>>(input, E, Wxf, b_lstm, gx);
        k_plstm <<<64,      256, 0, stream>>>(Whf, gx, Hx, Hb);
        k_wfrag <<<NCT,     256, 0, stream>>>(W_dense, Wf, VOCABN);
        k_dense <<<512,     256, 0, stream>>>(Hb, Wf, b_dense, S);
        k_target<<<BT / 8,  256, 0, stream>>>(Hb, Wf, b_dense, targets, S, out);
    }
}

// Round 2
// 379.889 us; speedup vs baseline: 1.0737x; 1.0737x over previous
//
#include <hip/hip_runtime.h>
#include <math.h>

// Problem constants (reference: VOCAB=10000, HID=256, B=64, T=64)
#define VOCABN 10000
#define HIDN   256
#define GATES  1024   // 4*HID
#define BN     64
#define TN     64
#define BT     4096   // B*T
#define NCT    625    // vocab col-tiles of 16 (10000 = 625*16 exactly)

typedef unsigned int       u32;
typedef unsigned short     u16;
typedef unsigned long long u64;
typedef float v4f __attribute__((ext_vector_type(4)));
typedef short v8s __attribute__((ext_vector_type(8)));

// Sentinel for the h-exchange ring: four bf16 lanes of 0xFFFF (= -NaN each).
// h = sigmoid*tanh products are finite with |h| < 1, so f2bf(h) can never be
// 0xFFFF; a packed u64 of real h data can never equal SENT.
#define SENT 0xFFFFFFFFFFFFFFFFULL

__device__ __forceinline__ float bf2f(u16 u) {
    return __uint_as_float(((u32)u) << 16);
}
__device__ __forceinline__ u16 f2bf(float f) {          // round-to-nearest-even
    u32 u = __float_as_uint(f);
    u += 0x7FFFu + ((u >> 16) & 1u);
    return (u16)(u >> 16);
}
__device__ __forceinline__ float fast_sigmoid(float x) {
    return 1.0f / (1.0f + __expf(-x));
}
__device__ __forceinline__ float fast_tanh(float x) {
    float e = __expf(-2.0f * fabsf(x));
    float t = (1.0f - e) / (1.0f + e);
    return copysignf(t, x);
}
__device__ __forceinline__ u64 llc_load(const u64* p) {
    return __hip_atomic_load(p, __ATOMIC_RELAXED, __HIP_MEMORY_SCOPE_AGENT);
}
__device__ __forceinline__ void llc_store(u64* p, u64 v) {
    __hip_atomic_store(p, v, __ATOMIC_RELAXED, __HIP_MEMORY_SCOPE_AGENT);
}

// ---------------------------------------------------------------------------
// fp32 [HIDN][ncols] tile c -> bf16 MFMA B-fragment layout [c][8 q][64 l][8].
// Fragment (c,q), lane l holds B[k = q*32 + (l>>4)*8 + j][n = c*16 + (l&15)].
// Plain uint4 stores (writer-L2 cached; cross-kernel visibility via the
// end-of-dispatch flush — consumers are always later launches).
// ---------------------------------------------------------------------------
__device__ __forceinline__ void wfrag_dev(
    const float* __restrict__ src, u16* __restrict__ dst, int ncols, int c,
    int t, u16 lt[HIDN][16])
{
    const float* s = src + (size_t)t * ncols + c * 16;
    #pragma unroll
    for (int j4 = 0; j4 < 4; ++j4) {
        float4 v = *(const float4*)(s + j4 * 4);
        lt[t][j4*4+0] = f2bf(v.x);
        lt[t][j4*4+1] = f2bf(v.y);
        lt[t][j4*4+2] = f2bf(v.z);
        lt[t][j4*4+3] = f2bf(v.w);
    }
    __syncthreads();
    #pragma unroll
    for (int h = 0; h < 2; ++h) {
        int f = t + h * 256;             // frag id = q*64 + l
        int q = f >> 6, l = f & 63;
        int m = l & 15, kb = q * 32 + ((l >> 4) & 3) * 8;
        u32 w[4];
        #pragma unroll
        for (int j = 0; j < 4; ++j)
            w[j] = (u32)lt[kb + 2*j][m] | ((u32)lt[kb + 2*j + 1][m] << 16);
        *(uint4*)(dst + (((size_t)c * 8 + q) * 64 + l) * 8) =
            make_uint4(w[0], w[1], w[2], w[3]);
    }
}

// ---------------------------------------------------------------------------
// wfrag for both W_lstm halves (128 blocks) — fallback-path prep. Blocks
// 0..63 also sentinel-fill the 4-deep Hx ring (16384 u64 = 64 blk x 256 thr).
// ---------------------------------------------------------------------------
__global__ __launch_bounds__(256) void k_wfrag2(
    const float* __restrict__ W_lstm,
    u16* __restrict__ Wxf, u16* __restrict__ Whf,
    u64* __restrict__ Hx64)          // [4*BN*HIDN/4] u64 exchange ring
{
    __shared__ u16 lt[HIDN][16];
    const int bid = blockIdx.x;
    if (bid < 64) {
        Hx64[(size_t)bid * 256 + threadIdx.x] = SENT;
        wfrag_dev(W_lstm, Wxf, GATES, bid, threadIdx.x, lt);
    } else {
        wfrag_dev(W_lstm + (size_t)HIDN * GATES, Whf, GATES, bid - 64,
                  threadIdx.x, lt);
    }
}

// ---------------------------------------------------------------------------
// ALL THREE weight transforms in one launch (753 blocks) — wide-ws path.
//   0..63: W_lstm x-part -> Wxf (+ Hx sentinel fill) | 64..127: h-part -> Whf
//   | 128..752: W_dense
// ---------------------------------------------------------------------------
__global__ __launch_bounds__(256) void k_wfrag3(
    const float* __restrict__ W_lstm,
    const float* __restrict__ W_dense,
    u16* __restrict__ Wxf, u16* __restrict__ Whf, u16* __restrict__ Wf,
    u64* __restrict__ Hx64)
{
    __shared__ u16 lt[HIDN][16];
    const int bid = blockIdx.x;
    if (bid < 64) {
        Hx64[(size_t)bid * 256 + threadIdx.x] = SENT;
        wfrag_dev(W_lstm, Wxf, GATES, bid, threadIdx.x, lt);
    } else if (bid < 128) {
        wfrag_dev(W_lstm + (size_t)HIDN * GATES, Whf, GATES, bid - 64,
                  threadIdx.x, lt);
    } else {
        wfrag_dev(W_dense, Wf, VOCABN, bid - 128, threadIdx.x, lt);
    }
}

// ---------------------------------------------------------------------------
// wfrag for W_dense (625 blocks) — fallback path, runs AFTER plstm (Wf
// aliases gx there).
// ---------------------------------------------------------------------------
__global__ __launch_bounds__(256) void k_wfrag(
    const float* __restrict__ src,   // [HIDN][ncols]
    u16*         __restrict__ dst,   // [nct][8][64][8]
    int ncols)
{
    __shared__ u16 lt[HIDN][16];
    wfrag_dev(src, dst, ncols, blockIdx.x, threadIdx.x, lt);
}

// ---------------------------------------------------------------------------
// Kernel 1 (MFMA): gates_x = E[idx] @ W_x + b_lstm. 256 blocks x 16 rows.
// gx stays fp32: bf16 gx cost plstm +14us (R9 vs R10 A/B).
// ---------------------------------------------------------------------------
__global__ __launch_bounds__(256) void k_xgates(
    const int*   __restrict__ idx,   // [BT]
    const float* __restrict__ E,     // [VOCAB][HIDN]
    const u16*   __restrict__ Wxf,   // [64][8][64][8]
    const float* __restrict__ bl,    // [GATES]
    float*       __restrict__ gx)    // [BT][GATES]
{
    const int r0   = blockIdx.x * 16;
    const int tid  = threadIdx.x;
    const int w    = tid >> 6, lane = tid & 63;
    const int m    = lane & 15, quad = lane >> 4;

    v8s a[8];
    {
        const float* e = E + (size_t)idx[r0 + m] * HIDN + quad * 8;
        #pragma unroll
        for (int q = 0; q < 8; ++q) {
            float4 x0 = *(const float4*)(e + q * 32);
            float4 x1 = *(const float4*)(e + q * 32 + 4);
            uint4 t4 = make_uint4(
                (u32)f2bf(x0.x) | ((u32)f2bf(x0.y) << 16),
                (u32)f2bf(x0.z) | ((u32)f2bf(x0.w) << 16),
                (u32)f2bf(x1.x) | ((u32)f2bf(x1.y) << 16),
                (u32)f2bf(x1.z) | ((u32)f2bf(x1.w) << 16));
            a[q] = *(v8s*)&t4;
        }
    }

    for (int c = w; c < GATES / 16; c += 4) {
        v4f acc = {0.f, 0.f, 0.f, 0.f};
        #pragma unroll
        for (int q = 0; q < 8; ++q) {
            v8s b = *(const v8s*)(Wxf + (((size_t)c * 8 + q) * 64 + lane) * 8);
            acc = __builtin_amdgcn_mfma_f32_16x16x32_bf16(a[q], b, acc, 0, 0, 0);
        }
        const int col = c * 16 + m;
        const float bv = bl[col];
        #pragma unroll
        for (int r = 0; r < 4; ++r)   // D: col=lane&15, row=quad*4+r (m89/m91)
            gx[(size_t)(r0 + quad * 4 + r) * GATES + col] = acc[r] + bv;
    }
}

// ---------------------------------------------------------------------------
// Kernel 2 (persistent MFMA LSTM — sentinel ring, BATCHED poll this round):
// 64 blocks = 4 row-groups(16 rows) x 16 unit-slices. W_h slice LDS-resident.
//
// R0 post-mortem: sentinel ring PASSED (ordering proof HW-validated) but the
// per-element serial `while(d[i]==SENT) reload` poll serialized dependent LLC
// round trips on arrival jitter (FETCH +9MB of poll reloads, +0.85us/step).
// This round: mask-based BATCHED re-poll — every round issues ALL pending
// reloads back-to-back (independent, full MLP), then re-checks. Each round
// ~1 pipelined LLC RT regardless of pending count; detect latency after the
// producer's publish ~<=1 round. Ordering/safety identical to R0:
//  * 4-deep ring; step t publishes buf t&3; consumed at t+1.
//  * preclear(buf (t+1)&3) issued at top of step t, drained by the mid-step
//    __syncthreads (vmcnt 0) BEFORE publish(t) -> observing data(t) implies
//    the clear is visible; observing data(t-2) before preclear(t) implies all
//    old readers of that buffer retired. No stale-generation acceptance.
//  * gl double-buffered (t&1) -> ONE __syncthreads per step.
// Runs ALONE (R7/R8: co-running dense cost this kernel 1.7x).
// ---------------------------------------------------------------------------
__global__ __launch_bounds__(256) void k_plstm(
    const u16*   __restrict__ Whf,   // [64 ct][8][64][8] h-part frags
    const float* __restrict__ gx,    // [BT][GATES]
    u16*                      Hx,    // [4][BN][HIDN] bf16 exchange ring (LLC)
    u16*         __restrict__ Hb)    // [BT][HIDN] bf16 output
{
    __shared__ uint4 Wl4[4 * 512];       // 32 KB: [ct][8 q][64 l][8] u16
    __shared__ float gl[2][4][16][16];   // 8 KB gate exchange, double-buffered

    const int tid  = threadIdx.x;
    const int rg   = blockIdx.x >> 4;    // row group: batch rows rg*16..+15
    const int ns   = blockIdx.x & 15;    // unit slice: units ns*16..+15
    const int u0   = ns * 16;
    const int w    = tid >> 6;           // wave = gate type (i,j,f,o)
    const int lane = tid & 63;
    const int m    = lane & 15, kq = lane >> 4;

    {   // load W_h slice: tiles c = w'*16 + ns, 8 KB contiguous each
        const uint4* src = (const uint4*)Whf;
        #pragma unroll
        for (int i = 0; i < 8; ++i) {
            int e  = tid + i * 256;          // [0, 2048)
            int ct = e >> 9, off = e & 511;  // 512 uint4 per tile
            Wl4[e] = src[(size_t)(ct * 16 + ns) * 512 + off];
        }
    }
    {   // zero gl[0] so t=0 reads 0 for the h@W_h term
        float* g0 = (float*)gl[0];
        #pragma unroll
        for (int j = 0; j < 4; ++j) g0[tid * 4 + j] = 0.0f;
    }
    __syncthreads();

    const u16* Wl = (const u16*)Wl4;

    const int r = tid >> 4, u = tid & 15;
    const int b = rg * 16 + r;                       // batch row
    const float* gxp = gx + (size_t)b * TN * GATES + u0 + u;
    u16* hbp = Hb + (size_t)b * TN * HIDN + u0 + u;
    const int hxw = b * HIDN + u0 + u;               // Hx elem offset (in-buf)
    const int aoff = (rg * 16 + m) * HIDN + kq * 8;  // a-frag elem offset
    u64* const hx64 = (u64*)Hx;
    // this block's publish slice as u64 indices (64 u64s, tid<64 clears them)
    const int cidx = (rg * 16 + (tid >> 2)) * (HIDN / 4) + ns * 4 + (tid & 3);

    float cstate = 0.0f;
    float4 gxr;
    gxr.x = gxp[0]; gxr.y = gxp[256]; gxr.z = gxp[512]; gxr.w = gxp[768];

    for (int t = 0; t < TN; ++t) {
        // prefetch next step's x-gates early (hide HBM latency)
        float4 gxn = gxr;
        if (t + 1 < TN) {
            const float* p = gxp + (size_t)(t + 1) * GATES;
            gxn.x = p[0]; gxn.y = p[256]; gxn.z = p[512]; gxn.w = p[768];
        }

        // pre-clear next publish buffer (ordering proof in header comment).
        // Fire-and-forget; drained by the __syncthreads below.
        if (t + 1 < TN && tid < 64)
            llc_store(hx64 + (size_t)((t + 1) & 3) * (BN * HIDN / 4) + cidx,
                      SENT);

        if (t > 0) {
            // BATCHED poll: data != SENT IS the signal. Every round issues
            // all still-pending loads in parallel (independent addresses),
            // then re-checks -> ~1 pipelined LLC RT per round.
            const u64* hsrc =
                (const u64*)(Hx + (size_t)((t - 1) & 3) * (BN * HIDN) + aoff);
            u64 d[16];
            #pragma unroll
            for (int q = 0; q < 8; ++q) {
                d[2 * q]     = llc_load(hsrc + q * 8);
                d[2 * q + 1] = llc_load(hsrc + q * 8 + 1);
            }
            u32 pend = 0xFFFFu;
            while (pend) {
                u32 np = 0;
                #pragma unroll
                for (int i = 0; i < 16; ++i)
                    if (d[i] == SENT) np |= (1u << i);
                if (np) {
                    #pragma unroll
                    for (int i = 0; i < 16; ++i)
                        if (np & (1u << i))
                            d[i] = llc_load(hsrc + (i >> 1) * 8 + (i & 1));
                }
                pend = np;
            }

            v4f acc = {0.f, 0.f, 0.f, 0.f};
            #pragma unroll
            for (int q = 0; q < 8; ++q) {
                union { u64 dd[2]; v8s v; } av;
                av.dd[0] = d[2 * q];
                av.dd[1] = d[2 * q + 1];
                v8s bf = *(const v8s*)(Wl + ((w * 8 + q) * 64 + lane) * 8);
                acc = __builtin_amdgcn_mfma_f32_16x16x32_bf16(av.v, bf, acc,
                                                              0, 0, 0);
            }
            #pragma unroll
            for (int rr = 0; rr < 4; ++rr)   // row = kq*4+rr, col(unit) = m
                gl[t & 1][w][kq * 4 + rr][m] = acc[rr];
        }
        __syncthreads();   // gl[t&1] ready; clear stores drained (vmcnt 0)
                           // BEFORE the data(t) publish below

        {   // cell update for (r, u); c stays in a register
            float ai = gl[t & 1][0][r][u] + gxr.x;
            float aj = gl[t & 1][1][r][u] + gxr.y;
            float af = gl[t & 1][2][r][u] + gxr.z;
            float ao = gl[t & 1][3][r][u] + gxr.w;
            float ig = fast_sigmoid(ai);
            float fg = fast_sigmoid(af + 1.0f);      // forget_bias = 1.0
            float og = fast_sigmoid(ao);
            float jt = fast_tanh(aj);
            cstate = fg * cstate + ig * jt;
            float hn = og * fast_tanh(cstate);
            u32 hv = f2bf(hn);
            hbp[(size_t)t * HIDN] = (u16)hv;

            if (t + 1 < TN) {
                // pack 4 consecutive units (same row, lanes tid..tid+3) into
                // one u64 and publish via relaxed agent atomic store -> LLC
                u32 p1 = __shfl_down(hv, 1);
                u32 p2 = __shfl_down(hv, 2);
                u32 p3 = __shfl_down(hv, 3);
                if ((tid & 3) == 0) {
                    u64 pk = (u64)(hv | (p1 << 16))
                           | ((u64)(p2 | (p3 << 16)) << 32);
                    u64* dst =
                        (u64*)(Hx + (size_t)(t & 3) * (BN * HIDN) + hxw);
                    llc_store(dst, pk);
                }
            }
        }
        // no end-of-step barrier: next iteration's gl write targets the
        // other gl buffer, and the step-t __syncthreads rendezvous already
        // separates it from step t-1's readers.
        gxr = gxn;
    }
}

// ---------------------------------------------------------------------------
// Kernel 3 (MFMA dense, 8-way vocab split — R14 verbatim): 512 blocks =
// 64 row-groups(64 rows, 4 register-resident a-frag row-tiles) x 8 vocab
// eighths (~640 KB Wf each, L2-resident per XCD under round-robin %8).
// NOTE: R16's fused target/final epilogue regressed +33us (conditional
// LLC store in the hot loop) — keep the sweep pure.
// ---------------------------------------------------------------------------
__global__ __launch_bounds__(256, 1) void k_dense(
    const u16*   __restrict__ Hb,    // [BT][HIDN] bf16
    const u16*   __restrict__ Wf,    // [625][8][64][8]
    const float* __restrict__ bd,    // [VOCAB]
    float*       __restrict__ S)     // [8][BT] partial sumexp
{
    __shared__ float Sl[64];
    const int bid = blockIdx.x;
    const int hv  = bid & 7;                    // vocab eighth (XCD-aligned)
    const int rg  = bid >> 3;                   // 0..63
    const int r0  = rg * 64;
    const int tid = threadIdx.x;
    const int w   = tid >> 6, lane = tid & 63;
    const int m   = lane & 15, kq = lane >> 4;

    if (tid < 64) Sl[tid] = 0.0f;

    v8s a[4][8];
    #pragma unroll
    for (int rt = 0; rt < 4; ++rt) {
        const u16* hrow = Hb + (size_t)(r0 + rt * 16 + m) * HIDN + kq * 8;
        #pragma unroll
        for (int q = 0; q < 8; ++q)
            a[rt][q] = *(const v8s*)(hrow + q * 32);
    }
    __syncthreads();

    float s[4][4] = {{0.f,0.f,0.f,0.f},{0.f,0.f,0.f,0.f},
                     {0.f,0.f,0.f,0.f},{0.f,0.f,0.f,0.f}};
    const int cbeg = (hv * NCT) >> 3;
    const int cend = ((hv + 1) * NCT) >> 3;
    for (int c = cbeg + w; c < cend; c += 4) {
        v4f acc[4] = {{0.f,0.f,0.f,0.f},{0.f,0.f,0.f,0.f},
                      {0.f,0.f,0.f,0.f},{0.f,0.f,0.f,0.f}};
        #pragma unroll
        for (int q = 0; q < 8; ++q) {
            v8s bq = *(const v8s*)(Wf + (((size_t)c * 8 + q) * 64 + lane) * 8);
            #pragma unroll
            for (int rt = 0; rt < 4; ++rt)
                acc[rt] = __builtin_amdgcn_mfma_f32_16x16x32_bf16(
                              a[rt][q], bq, acc[rt], 0, 0, 0);
        }
        const float bv = bd[c * 16 + m];
        #pragma unroll
        for (int rt = 0; rt < 4; ++rt)
            #pragma unroll
            for (int r = 0; r < 4; ++r)
                s[rt][r] += __expf(acc[rt][r] + bv);
    }

    #pragma unroll
    for (int rt = 0; rt < 4; ++rt)
        #pragma unroll
        for (int r = 0; r < 4; ++r)
            atomicAdd(&Sl[rt * 16 + kq * 4 + r], s[rt][r]);
    __syncthreads();
    if (tid < 64) S[(size_t)hv * BT + r0 + tid] = Sl[tid];
}

// ---------------------------------------------------------------------------
// Kernel 4 (target + final fused — R14 verbatim): per row, dot h with the
// target's W column (32 thr/row), then ppl = exp(log(sum S) - logit).
// ---------------------------------------------------------------------------
__global__ __launch_bounds__(256) void k_target(
    const u16*   __restrict__ Hb,
    const u16*   __restrict__ Wf,
    const float* __restrict__ bd,
    const int*   __restrict__ tgt,
    const float* __restrict__ S,     // [8][BT]
    float*       __restrict__ out)   // [BT]
{
    const int tid = threadIdx.x;
    const int row = blockIdx.x * 8 + (tid >> 5);
    const int t   = tid & 31;
    const int q   = t >> 2, lq = t & 3;
    const int v   = tgt[row];
    const int c   = v >> 4, vm = v & 15;
    const int kb  = q * 32 + lq * 8;

    v8s h  = *(const v8s*)(Hb + (size_t)row * HIDN + kb);
    v8s wv = *(const v8s*)(Wf + (((size_t)c * 8 + q) * 64 + lq * 16 + vm) * 8);
    float acc = 0.0f;
    #pragma unroll
    for (int j = 0; j < 8; ++j)
        acc = fmaf(bf2f((u16)h[j]), bf2f((u16)wv[j]), acc);
    #pragma unroll
    for (int off = 16; off >= 1; off >>= 1)
        acc += __shfl_down(acc, off, 32);
    if (t == 0) {
        float tlv = acc + bd[v];
        float sum = 0.0f;
        #pragma unroll
        for (int p = 0; p < 8; ++p) sum += S[(size_t)p * BT + row];
        out[row] = __expf(__logf(sum) - tlv);
    }
}

// ---------------------------------------------------------------------------
extern "C" void kernel_launch(void* const* d_in, const int* in_sizes, int n_in,
                              void* d_out, int out_size, void* d_ws, size_t ws_size,
                              hipStream_t stream) {
    const int*   input   = (const int*)  d_in[0];   // [B,T]
    const int*   targets = (const int*)  d_in[1];   // [B,T]
    const float* E       = (const float*)d_in[2];   // [VOCAB,HID]
    const float* W_lstm  = (const float*)d_in[3];   // [2H,4H]
    const float* b_lstm  = (const float*)d_in[4];   // [4H]
    const float* W_dense = (const float*)d_in[5];   // [HID,VOCAB]
    const float* b_dense = (const float*)d_in[6];   // [VOCAB]
    float* out = (float*)d_out;                     // [B,T] perplexity

    char* ws = (char*)d_ws;
    const bool wide = (ws_size >= ((size_t)25 << 20));

    if (wide) {
        // 5-node layout: Wf gets its own region; ALL weight transforms in
        // one prep node before xgates. (~24.5 MB)
        //  [0,16M): gx | [16M,21.12M): Wf | [21.25M,23.25M): Hb
        //  [23.25M,+512K): Whf | [23.75M,+512K): Wxf
        //  [24.25M,+128K): Hx (4-deep ring) | [24.25M+128K,+128K): S
        float* gx  = (float*)ws;
        u16*   Wf  = (u16*)(ws + ((size_t)16 << 20));
        u16*   Hb  = (u16*)(ws + ((size_t)21 << 20) + ((size_t)256 << 10));
        u16*   Whf = (u16*)(ws + ((size_t)23 << 20) + ((size_t)256 << 10));
        u16*   Wxf = (u16*)(ws + ((size_t)23 << 20) + ((size_t)768 << 10));
        u16*   Hx  = (u16*)(ws + ((size_t)24 << 20) + ((size_t)256 << 10));
        float* S   = (float*)(ws + ((size_t)24 << 20) + ((size_t)384 << 10));

        k_wfrag3<<<753,     256, 0, stream>>>(W_lstm, W_dense, Wxf, Whf, Wf,
                                              (u64*)Hx);
        k_xgates<<<BT / 16, 256, 0, stream>>>(input, E, Wxf, b_lstm, gx);
        k_plstm <<<64,      256, 0, stream>>>(Whf, gx, Hx, Hb);
        k_dense <<<512,     256, 0, stream>>>(Hb, Wf, b_dense, S);
        k_target<<<BT / 8,  256, 0, stream>>>(Hb, Wf, b_dense, targets, S, out);
    } else {
        // 6-node fallback (Wf aliases gx after plstm).
        //  [0,16M): gx/Wf | [16M,18M): Hb | [18M,+512K): Whf
        //  [18.5M,+512K): Wxf | [19M,+128K): Hx | [19M+128K,+128K): S
        float* gx  = (float*)ws;
        u16*   Wf  = (u16*)ws;
        u16*   Hb  = (u16*)(ws + ((size_t)16 << 20));
        u16*   Whf = (u16*)(ws + ((size_t)18 << 20));
        u16*   Wxf = (u16*)(ws + ((size_t)18 << 20) + ((size_t)512 << 10));
        u16*   Hx  = (u16*)(ws + ((size_t)19 << 20));
        float* S   = (float*)(ws + ((size_t)19 << 20) + ((size_t)128 << 10));

        k_wfrag2<<<128,     256, 0, stream>>>(W_lstm, Wxf, Whf, (u64*)Hx);
        k_xgates<<<BT / 16, 256, 0, stream>>>(input, E, Wxf, b_lstm, gx);
        k_plstm <<<64,      256, 0, stream>>>(Whf, gx, Hx, Hb);
        k_wfrag <<<NCT,     256, 0, stream>>>(W_dense, Wf, VOCABN);
        k_dense <<<512,     256, 0, stream>>>(Hb, Wf, b_dense, S);
        k_target<<<BT / 8,  256, 0, stream>>>(Hb, Wf, b_dense, targets, S, out);
    }
}